// Round 10
// baseline (146.167 us; speedup 1.0000x reference)
//
#include <hip/hip_runtime.h>
#include <stdint.h>

// WeightedNeighborSampler — exact reproduction of
// jax.random.categorical(key(42), log(w)) (partitionable threefry, XOR-fold).
//
// Round-10: decisive ILP probe. tf_bits4 advances the lane's 4 cipher chains
// ROUND-BY-ROUND in lockstep at the statement level, so the machine scheduler
// must keep 4 live chain states (R7-R9 showed it re-serializes whole-function
// calls back to VGPR=24). launch_bounds min-waves dropped to uncap regalloc
// (VGPR est. 40-56, still <=64 -> 8 waves/SIMD). All numerics bit-identical
// to the validated lineage (pure integer statement reordering).

#define MAXDEG 128

__device__ __forceinline__ uint32_t rotl32(uint32_t x, int r) {
  return __builtin_rotateleft32(x, r);  // v_alignbit_b32
}

// ---- 4-way lockstep threefry2x32, key (0,42), counters (0, i..i+3) --------
// Returns out0^out1 per chain (JAX partitionable 32-bit fold).
#define RND4(rot)                                                            \
  a1 = rotl32(a1, rot) ^ a0; b1 = rotl32(b1, rot) ^ b0;                      \
  c1 = rotl32(c1, rot) ^ c0; d1 = rotl32(d1, rot) ^ d0;
#define ADD4 a0 += a1; b0 += b1; c0 += c1; d0 += d1;
#define INJ4(k1add, k0add)                                                   \
  a1 += (k1add); b1 += (k1add); c1 += (k1add); d1 += (k1add);                \
  a0 = a0 + a1 + (k0add); b0 = b0 + b1 + (k0add);                            \
  c0 = c0 + c1 + (k0add); d0 = d0 + d1 + (k0add);

__device__ __forceinline__ void tf_bits4(uint32_t i, uint32_t r[4]) {
  uint32_t a1 = i + 42u, b1 = i + 43u, c1 = i + 44u, d1 = i + 45u;
  uint32_t a0 = a1, b0 = b1, c0 = c1, d0 = d1;   // round 1: x0 = 0 + x1
  RND4(13) ADD4 RND4(15) ADD4 RND4(26) ADD4 RND4(6)
  INJ4(0x1BD11BF1u, 42u)                          // inj(ks1, ks2+1)
  RND4(17) ADD4 RND4(29) ADD4 RND4(16) ADD4 RND4(24)
  INJ4(2u, 0x1BD11BF0u)                           // inj(ks2, ks0+2)
  RND4(13) ADD4 RND4(15) ADD4 RND4(26) ADD4 RND4(6)
  INJ4(45u, 0u)                                   // inj(ks0, ks1+3), ks0==0
  RND4(17) ADD4 RND4(29) ADD4 RND4(16) ADD4 RND4(24)
  INJ4(0x1BD11BF4u, 42u)                          // inj(ks1, ks2+4)
  RND4(13) ADD4 RND4(15) ADD4 RND4(26) ADD4 RND4(6)
  r[0] = (a0 + 0x1BD11BF0u) ^ (a1 + 5u);          // final inj(ks2, ks0+5)
  r[1] = (b0 + 0x1BD11BF0u) ^ (b1 + 5u);
  r[2] = (c0 + 0x1BD11BF0u) ^ (c1 + 5u);
  r[3] = (d0 + 0x1BD11BF0u) ^ (d1 + 5u);
}

// Single-chain version (cold resolve path only).
__device__ __forceinline__ uint32_t tf_bits(uint32_t i) {
  uint32_t x0, x1;
  x1 = i + 42u; x0 = x1;
  x1 = rotl32(x1, 13) ^ x0;
  x0 += x1; x1 = rotl32(x1, 15) ^ x0;
  x0 += x1; x1 = rotl32(x1, 26) ^ x0;
  x0 += x1; x1 = rotl32(x1,  6) ^ x0;
  x1 += 0x1BD11BF1u; x0 = x0 + x1 + 42u;
  x1 = rotl32(x1, 17) ^ x0;
  x0 += x1; x1 = rotl32(x1, 29) ^ x0;
  x0 += x1; x1 = rotl32(x1, 16) ^ x0;
  x0 += x1; x1 = rotl32(x1, 24) ^ x0;
  x1 += 2u; x0 = x0 + x1 + 0x1BD11BF0u;
  x1 = rotl32(x1, 13) ^ x0;
  x0 += x1; x1 = rotl32(x1, 15) ^ x0;
  x0 += x1; x1 = rotl32(x1, 26) ^ x0;
  x0 += x1; x1 = rotl32(x1,  6) ^ x0;
  x1 += 45u; x0 = x0 + x1;
  x1 = rotl32(x1, 17) ^ x0;
  x0 += x1; x1 = rotl32(x1, 29) ^ x0;
  x0 += x1; x1 = rotl32(x1, 16) ^ x0;
  x0 += x1; x1 = rotl32(x1, 24) ^ x0;
  x1 += 0x1BD11BF4u; x0 = x0 + x1 + 42u;
  x1 = rotl32(x1, 13) ^ x0;
  x0 += x1; x1 = rotl32(x1, 15) ^ x0;
  x0 += x1; x1 = rotl32(x1, 26) ^ x0;
  x0 += x1; x1 = rotl32(x1,  6) ^ x0;
  return (x0 + 0x1BD11BF0u) ^ (x1 + 5u);
}

// JAX uniform(minval=tiny, maxval=1) float from 32 random bits.
__device__ __forceinline__ float uniform_from_bits(uint32_t bits) {
  uint32_t fb = (bits >> 9) | 0x3f800000u;
  float f = __uint_as_float(fb) - 1.0f;     // {0} U [2^-23, 1)
  return fmaxf(f, 1.17549435e-38f);         // == (f==0 ? tiny : f)
}

// f32 screen score in log2 space: lwp - ln2*log2(-log2(u)).
__device__ __forceinline__ float zscore(float lwp, uint32_t bits) {
  const float l = __log2f(uniform_from_bits(bits));
  const float t = __log2f(-l);
  return __builtin_fmaf(-0.69314718056f, t, lwp);
}

// v_max with DPP row_ror:K (all-reduce within each 16-lane row).
template <int CTRL>
__device__ __forceinline__ float dpp_max_step(float z) {
  const int t = __builtin_amdgcn_update_dpp(0, __float_as_int(z), CTRL, 0xF, 0xF, true);
  return fmaxf(z, __int_as_float(t));
}

// xor-swizzle max (BitMode and=0x1F confines to 32-lane halves).
__device__ __forceinline__ float swz_max16(float z) {
  return fmaxf(z, __int_as_float(
      __builtin_amdgcn_ds_swizzle(__float_as_int(z), 0x401F)));  // xor 16
}

// Cold exact-f64 argmax for one sample (both halves at once). Byte-identical
// math to the round-2-validated chain. Returns bd (uniform within each half).
__device__ __attribute__((noinline)) int resolve_f64(
    float4 wv, uint32_t sbase, int l) {
  const uint32_t bits0 = tf_bits(sbase + 0u);
  const uint32_t bits1 = tf_bits(sbase + 1u);
  const uint32_t bits2 = tf_bits(sbase + 2u);
  const uint32_t bits3 = tf_bits(sbase + 3u);
  double bz = log((double)wv.x) - log(-log((double)uniform_from_bits(bits0)));
  int bd = 4 * l;
  const double Z1 = log((double)wv.y) - log(-log((double)uniform_from_bits(bits1)));
  if (Z1 > bz) { bz = Z1; bd = 4 * l + 1; }
  const double Z2 = log((double)wv.z) - log(-log((double)uniform_from_bits(bits2)));
  if (Z2 > bz) { bz = Z2; bd = 4 * l + 2; }
  const double Z3 = log((double)wv.w) - log(-log((double)uniform_from_bits(bits3)));
  if (Z3 > bz) { bz = Z3; bd = 4 * l + 3; }
  #pragma unroll
  for (int m = 1; m < 32; m <<= 1) {   // xor masks stay within 32-halves
    const double oz = __shfl_xor(bz, m);
    const int od = __shfl_xor(bd, m);
    if (oz > bz || (oz == bz && od < bd)) { bz = oz; bd = od; }
  }
  return bd;
}

__global__ __launch_bounds__(256) void wns_kernel(
    const float* __restrict__ adj_weight,
    const int* __restrict__ adj_info,
    const int* __restrict__ ids,
    int* __restrict__ out,
    int batch, int nsamp) {
  const int lane = threadIdx.x & 63;
  const int l = lane & 31;                         // lane within row
  const int wid = blockIdx.x * 4 + (threadIdx.x >> 6);
  if (2 * wid >= batch) return;                    // wave-uniform guard
  const int b = 2 * wid + (lane >> 5);             // lanes 0-31: b0, 32-63: b1

  const int nid = ids[b];                          // < 1e5, 32-bit math ok
  const float4 wv = *(const float4*)(adj_weight + nid * MAXDEG + 4 * l);
  // lwp = log(w) + ln2*log2(ln2), once per b (reused for 25 samples).
  const float lwp0 = __logf(wv.x) + 0.36651292f;
  const float lwp1 = __logf(wv.y) + 0.36651292f;
  const float lwp2 = __logf(wv.z) + 0.36651292f;
  const float lwp3 = __logf(wv.w) + 0.36651292f;

  uint32_t sbase = (uint32_t)b * 128u + (uint32_t)(4 * l);
  const uint32_t sstep = (uint32_t)batch * 128u;

  uint32_t flagA = 0u, flagB = 0u;   // wave-uniform -> SGPR
  int dAcc = 0;                      // lane s: row-A d(s); lane 32+s: row-B d(s)

  #pragma unroll 1
  for (int s = 0; s < nsamp; ++s, sbase += sstep) {
    // 4 cipher chains, statement-interleaved (forces 4-way ILP in schedule)
    uint32_t bits[4];
    tf_bits4(sbase, bits);

    const float z0 = zscore(lwp0, bits[0]);
    const float z1 = zscore(lwp1, bits[1]);
    const float z2 = zscore(lwp2, bits[2]);
    const float z3 = zscore(lwp3, bits[3]);

    // row max: local 4-way, DPP ror{1,2,4,8} within 16, one xor-16 swizzle
    float zmax = fmaxf(fmaxf(fmaxf(z0, z1), z2), z3);
    zmax = dpp_max_step<0x121>(zmax);  // row_ror:1
    zmax = dpp_max_step<0x122>(zmax);  // row_ror:2
    zmax = dpp_max_step<0x124>(zmax);  // row_ror:4
    zmax = dpp_max_step<0x128>(zmax);  // row_ror:8
    zmax = swz_max16(zmax);            // xor 16 (within 32-half)

    // Screen ballots: candidates within 3e-4 of the row max
    const float thr = zmax - 3.0e-4f;
    const unsigned long long m0 = __ballot(z0 > thr);
    const unsigned long long m1 = __ballot(z1 > thr);
    const unsigned long long m2 = __ballot(z2 > thr);
    const unsigned long long m3 = __ballot(z3 > thr);
    const uint32_t a0 = (uint32_t)m0, a1 = (uint32_t)m1,
                   a2 = (uint32_t)m2, a3 = (uint32_t)m3;
    const uint32_t c0 = (uint32_t)(m0 >> 32), c1 = (uint32_t)(m1 >> 32),
                   c2 = (uint32_t)(m2 >> 32), c3 = (uint32_t)(m3 >> 32);
    const int cntA = __popc(a0) + __popc(a1) + __popc(a2) + __popc(a3);
    const int cntB = __popc(c0) + __popc(c1) + __popc(c2) + __popc(c3);

    // fast-path argmax (uniform per half; valid when cnt==1, patched later)
    const int dA = a0 ? 4 * __builtin_ctz(a0)
                 : a1 ? 4 * __builtin_ctz(a1) + 1
                 : a2 ? 4 * __builtin_ctz(a2) + 2
                 : a3 ? 4 * __builtin_ctz(a3) + 3 : 0;
    const int dB = c0 ? 4 * __builtin_ctz(c0)
                 : c1 ? 4 * __builtin_ctz(c1) + 1
                 : c2 ? 4 * __builtin_ctz(c2) + 2
                 : c3 ? 4 * __builtin_ctz(c3) + 3 : 0;
    // deposit: lane s <- dA, lane 32+s <- dB
    const int dSel = (lane < 32) ? dA : dB;
    dAcc = ((lane & 31) == s) ? dSel : dAcc;

    flagA |= (cntA != 1) ? (1u << s) : 0u;   // SALU bookkeeping
    flagB |= (cntB != 1) ? (1u << s) : 0u;
  }

  // Cold exact resolve of flagged samples (expected ~0 per wave).
  const uint32_t rowbase = (uint32_t)b * 128u + (uint32_t)(4 * l);
  for (uint32_t m = flagA | flagB; m; m &= m - 1u) {
    const int s = __builtin_ctz(m);
    const int bd = resolve_f64(wv, rowbase + (uint32_t)s * sstep, l);
    const int bdA = __shfl(bd, 0);     // row-A winner (broadcast)
    const int bdB = __shfl(bd, 32);    // row-B winner (broadcast)
    if (((flagA >> s) & 1u) && lane == s) dAcc = bdA;
    if (((flagB >> s) & 1u) && lane == s + 32) dAcc = bdB;
  }

  // Epilogue: one coalesced gather + one contiguous store per row.
  if (l < nsamp) {
    out[b * nsamp + l] = adj_info[nid * MAXDEG + dAcc];
  }
}

extern "C" void kernel_launch(void* const* d_in, const int* in_sizes, int n_in,
                              void* d_out, int out_size, void* d_ws, size_t ws_size,
                              hipStream_t stream) {
  const float* adj_weight = (const float*)d_in[0];
  const int* adj_info = (const int*)d_in[1];
  const int* ids = (const int*)d_in[2];
  int batch = in_sizes[2];
  int nsamp = out_size / batch;             // 25 (<=32 required by flag masks)
  int waves = (batch + 1) / 2;              // 2 rows (b) per wave
  int blocks = (waves + 3) / 4;             // 4 waves per block
  wns_kernel<<<blocks, 256, 0, stream>>>(adj_weight, adj_info, ids,
                                         (int*)d_out, batch, nsamp);
}

// Round 11
// 144.920 us; speedup vs baseline: 1.0086x; 1.0086x over previous
//
#include <hip/hip_runtime.h>
#include <stdint.h>

// WeightedNeighborSampler — exact reproduction of
// jax.random.categorical(key(42), log(w)) (partitionable threefry, XOR-fold).
//
// Round-11: grid-shape probe. Code identical to R10; only the launch shape
// changes: 1024-thread blocks (16 waves) -> 512 workgroups instead of 2048.
// Theory: with exactly one resident generation, CP dispatch ramp + drain is
// the ~50% occupancy loss seen in counters (R2: 102k blocks -> 91% occ;
// R3: 4096 -> 73%; R4+: 2048 -> 52%). Fewer, fatter blocks cut dispatch
// events 4x at unchanged residency (8192 waves = 32/CU). No barriers, no
// LDS, wave-uniform guard -> bit-identical output.

#define MAXDEG 128

__device__ __forceinline__ uint32_t rotl32(uint32_t x, int r) {
  return __builtin_rotateleft32(x, r);  // v_alignbit_b32
}

// threefry2x32, key (0, 42), counter (0, i); returns out0 ^ out1 (JAX
// partitionable 32-bit fold). ks0=0, ks1=42, ks2=0x1BD11BF0.
__device__ __forceinline__ uint32_t tf_bits(uint32_t i) {
  uint32_t x0, x1;
  x1 = i + 42u; x0 = x1;        // round 1: x0 = 0 + x1
  x1 = rotl32(x1, 13) ^ x0;
  x0 += x1; x1 = rotl32(x1, 15) ^ x0;
  x0 += x1; x1 = rotl32(x1, 26) ^ x0;
  x0 += x1; x1 = rotl32(x1,  6) ^ x0;
  x1 += 0x1BD11BF1u; x0 = x0 + x1 + 42u;      // inj(ks1, ks2+1)
  x1 = rotl32(x1, 17) ^ x0;
  x0 += x1; x1 = rotl32(x1, 29) ^ x0;
  x0 += x1; x1 = rotl32(x1, 16) ^ x0;
  x0 += x1; x1 = rotl32(x1, 24) ^ x0;
  x1 += 2u; x0 = x0 + x1 + 0x1BD11BF0u;       // inj(ks2, ks0+2)
  x1 = rotl32(x1, 13) ^ x0;
  x0 += x1; x1 = rotl32(x1, 15) ^ x0;
  x0 += x1; x1 = rotl32(x1, 26) ^ x0;
  x0 += x1; x1 = rotl32(x1,  6) ^ x0;
  x1 += 45u; x0 = x0 + x1;                    // inj(ks0, ks1+3), ks0==0
  x1 = rotl32(x1, 17) ^ x0;
  x0 += x1; x1 = rotl32(x1, 29) ^ x0;
  x0 += x1; x1 = rotl32(x1, 16) ^ x0;
  x0 += x1; x1 = rotl32(x1, 24) ^ x0;
  x1 += 0x1BD11BF4u; x0 = x0 + x1 + 42u;      // inj(ks1, ks2+4)
  x1 = rotl32(x1, 13) ^ x0;
  x0 += x1; x1 = rotl32(x1, 15) ^ x0;
  x0 += x1; x1 = rotl32(x1, 26) ^ x0;
  x0 += x1; x1 = rotl32(x1,  6) ^ x0;
  return (x0 + 0x1BD11BF0u) ^ (x1 + 5u);      // final inj(ks2, ks0+5) + fold
}

// JAX uniform(minval=tiny, maxval=1) float from 32 random bits.
__device__ __forceinline__ float uniform_from_bits(uint32_t bits) {
  uint32_t fb = (bits >> 9) | 0x3f800000u;
  float f = __uint_as_float(fb) - 1.0f;     // {0} U [2^-23, 1)
  return fmaxf(f, 1.17549435e-38f);         // == (f==0 ? tiny : f)
}

// f32 screen score in log2 space: lwp - ln2*log2(-log2(u)).
__device__ __forceinline__ float zscore(float lwp, uint32_t bits) {
  const float l = __log2f(uniform_from_bits(bits));
  const float t = __log2f(-l);
  return __builtin_fmaf(-0.69314718056f, t, lwp);
}

// v_max with DPP row_ror:K (all-reduce within each 16-lane row).
template <int CTRL>
__device__ __forceinline__ float dpp_max_step(float z) {
  const int t = __builtin_amdgcn_update_dpp(0, __float_as_int(z), CTRL, 0xF, 0xF, true);
  return fmaxf(z, __int_as_float(t));
}

// xor-swizzle max (BitMode and=0x1F confines to 32-lane halves).
__device__ __forceinline__ float swz_max16(float z) {
  return fmaxf(z, __int_as_float(
      __builtin_amdgcn_ds_swizzle(__float_as_int(z), 0x401F)));  // xor 16
}

// Cold exact-f64 argmax for one sample (both halves at once). Byte-identical
// math to the round-2-validated chain. Returns bd (uniform within each half).
__device__ __attribute__((noinline)) int resolve_f64(
    float4 wv, uint32_t sbase, int l) {
  const uint32_t bits0 = tf_bits(sbase + 0u);
  const uint32_t bits1 = tf_bits(sbase + 1u);
  const uint32_t bits2 = tf_bits(sbase + 2u);
  const uint32_t bits3 = tf_bits(sbase + 3u);
  double bz = log((double)wv.x) - log(-log((double)uniform_from_bits(bits0)));
  int bd = 4 * l;
  const double Z1 = log((double)wv.y) - log(-log((double)uniform_from_bits(bits1)));
  if (Z1 > bz) { bz = Z1; bd = 4 * l + 1; }
  const double Z2 = log((double)wv.z) - log(-log((double)uniform_from_bits(bits2)));
  if (Z2 > bz) { bz = Z2; bd = 4 * l + 2; }
  const double Z3 = log((double)wv.w) - log(-log((double)uniform_from_bits(bits3)));
  if (Z3 > bz) { bz = Z3; bd = 4 * l + 3; }
  #pragma unroll
  for (int m = 1; m < 32; m <<= 1) {   // xor masks stay within 32-halves
    const double oz = __shfl_xor(bz, m);
    const int od = __shfl_xor(bd, m);
    if (oz > bz || (oz == bz && od < bd)) { bz = oz; bd = od; }
  }
  return bd;
}

__global__ __launch_bounds__(1024) void wns_kernel(
    const float* __restrict__ adj_weight,
    const int* __restrict__ adj_info,
    const int* __restrict__ ids,
    int* __restrict__ out,
    int batch, int nsamp) {
  const int lane = threadIdx.x & 63;
  const int l = lane & 31;                         // lane within row
  const int wid = blockIdx.x * 16 + (threadIdx.x >> 6);  // 16 waves/block
  if (2 * wid >= batch) return;                    // wave-uniform guard
  const int b = 2 * wid + (lane >> 5);             // lanes 0-31: b0, 32-63: b1

  const int nid = ids[b];                          // < 1e5, 32-bit math ok
  const float4 wv = *(const float4*)(adj_weight + nid * MAXDEG + 4 * l);
  // lwp = log(w) + ln2*log2(ln2), once per b (reused for 25 samples).
  const float lwp0 = __logf(wv.x) + 0.36651292f;
  const float lwp1 = __logf(wv.y) + 0.36651292f;
  const float lwp2 = __logf(wv.z) + 0.36651292f;
  const float lwp3 = __logf(wv.w) + 0.36651292f;

  uint32_t sbase = (uint32_t)b * 128u + (uint32_t)(4 * l);
  const uint32_t sstep = (uint32_t)batch * 128u;

  uint32_t flagA = 0u, flagB = 0u;   // wave-uniform -> SGPR
  int dAcc = 0;                      // lane s: row-A d(s); lane 32+s: row-B d(s)

  #pragma unroll 1
  for (int s = 0; s < nsamp; ++s, sbase += sstep) {
    const uint32_t bits0 = tf_bits(sbase + 0u);
    const uint32_t bits1 = tf_bits(sbase + 1u);
    const uint32_t bits2 = tf_bits(sbase + 2u);
    const uint32_t bits3 = tf_bits(sbase + 3u);

    const float z0 = zscore(lwp0, bits0);
    const float z1 = zscore(lwp1, bits1);
    const float z2 = zscore(lwp2, bits2);
    const float z3 = zscore(lwp3, bits3);

    // row max: local 4-way, DPP ror{1,2,4,8} within 16, one xor-16 swizzle
    float zmax = fmaxf(fmaxf(fmaxf(z0, z1), z2), z3);
    zmax = dpp_max_step<0x121>(zmax);  // row_ror:1
    zmax = dpp_max_step<0x122>(zmax);  // row_ror:2
    zmax = dpp_max_step<0x124>(zmax);  // row_ror:4
    zmax = dpp_max_step<0x128>(zmax);  // row_ror:8
    zmax = swz_max16(zmax);            // xor 16 (within 32-half)

    // Screen ballots: candidates within 3e-4 of the row max
    const float thr = zmax - 3.0e-4f;
    const unsigned long long m0 = __ballot(z0 > thr);
    const unsigned long long m1 = __ballot(z1 > thr);
    const unsigned long long m2 = __ballot(z2 > thr);
    const unsigned long long m3 = __ballot(z3 > thr);
    const uint32_t a0 = (uint32_t)m0, a1 = (uint32_t)m1,
                   a2 = (uint32_t)m2, a3 = (uint32_t)m3;
    const uint32_t c0 = (uint32_t)(m0 >> 32), c1 = (uint32_t)(m1 >> 32),
                   c2 = (uint32_t)(m2 >> 32), c3 = (uint32_t)(m3 >> 32);
    const int cntA = __popc(a0) + __popc(a1) + __popc(a2) + __popc(a3);
    const int cntB = __popc(c0) + __popc(c1) + __popc(c2) + __popc(c3);

    // fast-path argmax (uniform per half; valid when cnt==1, patched later)
    const int dA = a0 ? 4 * __builtin_ctz(a0)
                 : a1 ? 4 * __builtin_ctz(a1) + 1
                 : a2 ? 4 * __builtin_ctz(a2) + 2
                 : a3 ? 4 * __builtin_ctz(a3) + 3 : 0;
    const int dB = c0 ? 4 * __builtin_ctz(c0)
                 : c1 ? 4 * __builtin_ctz(c1) + 1
                 : c2 ? 4 * __builtin_ctz(c2) + 2
                 : c3 ? 4 * __builtin_ctz(c3) + 3 : 0;
    // deposit: lane s <- dA, lane 32+s <- dB
    const int dSel = (lane < 32) ? dA : dB;
    dAcc = ((lane & 31) == s) ? dSel : dAcc;

    flagA |= (cntA != 1) ? (1u << s) : 0u;   // SALU bookkeeping
    flagB |= (cntB != 1) ? (1u << s) : 0u;
  }

  // Cold exact resolve of flagged samples (expected ~0 per wave).
  const uint32_t rowbase = (uint32_t)b * 128u + (uint32_t)(4 * l);
  for (uint32_t m = flagA | flagB; m; m &= m - 1u) {
    const int s = __builtin_ctz(m);
    const int bd = resolve_f64(wv, rowbase + (uint32_t)s * sstep, l);
    const int bdA = __shfl(bd, 0);     // row-A winner (broadcast)
    const int bdB = __shfl(bd, 32);    // row-B winner (broadcast)
    if (((flagA >> s) & 1u) && lane == s) dAcc = bdA;
    if (((flagB >> s) & 1u) && lane == s + 32) dAcc = bdB;
  }

  // Epilogue: one coalesced gather + one contiguous store per row.
  if (l < nsamp) {
    out[b * nsamp + l] = adj_info[nid * MAXDEG + dAcc];
  }
}

extern "C" void kernel_launch(void* const* d_in, const int* in_sizes, int n_in,
                              void* d_out, int out_size, void* d_ws, size_t ws_size,
                              hipStream_t stream) {
  const float* adj_weight = (const float*)d_in[0];
  const int* adj_info = (const int*)d_in[1];
  const int* ids = (const int*)d_in[2];
  int batch = in_sizes[2];
  int nsamp = out_size / batch;             // 25 (<=32 required by flag masks)
  int waves = (batch + 1) / 2;              // 2 rows (b) per wave
  int blocks = (waves + 15) / 16;           // 16 waves per 1024-thread block
  wns_kernel<<<blocks, 1024, 0, stream>>>(adj_weight, adj_info, ids,
                                          (int*)d_out, batch, nsamp);
}